// Round 6
// baseline (47.498 us; speedup 1.0000x reference)
//
#include <hip/hip_runtime.h>
#include <hip/hip_bf16.h>

typedef float f32x4 __attribute__((ext_vector_type(4)));
typedef float f32x16 __attribute__((ext_vector_type(16)));
typedef short s16x8 __attribute__((ext_vector_type(8)));
typedef unsigned int u32x4 __attribute__((ext_vector_type(4)));

__device__ __forceinline__ short f2bf(float v) {
    __hip_bfloat16 h = __float2bfloat16(v);
    return __builtin_bit_cast(short, h);
}
__device__ __forceinline__ unsigned cvtpk(float lo, float hi) {
    unsigned r;
    asm("v_cvt_pk_bf16_f32 %0, %1, %2" : "=v"(r) : "v"(lo), "v"(hi));
    return r;
}
// v_permlane32_swap_b32: x <- {x_lo, y_lo}, y <- {x_hi, y_hi}
__device__ __forceinline__ void swap32(unsigned &x, unsigned &y) {
    asm("v_permlane32_swap_b32 %0, %1" : "+v"(x), "+v"(y));
}

// Kernel 1: xa[a][k] = b1[k] + sum_d x[a][d]*W1[d][k];  yb[b][k] = sum_d y[b][d]*W1[128+d][k]
__global__ __launch_bounds__(128) void precompute_kernel(
    const float* __restrict__ x, const float* __restrict__ y,
    const float* __restrict__ W1, const float* __restrict__ b1,
    float* __restrict__ xa, float* __restrict__ yb)
{
    __shared__ float rows[8][128];
    const int bid = blockIdx.x;
    const int k = threadIdx.x;
    const bool is_x = bid < 128;
    const int r0 = (is_x ? bid : bid - 128) * 8;
    const float* src = (is_x ? x : y) + (size_t)r0 * 128;
    const float* w = is_x ? W1 : (W1 + 128 * 128);
#pragma unroll
    for (int r = 0; r < 8; ++r) rows[r][k] = src[r * 128 + k];
    __syncthreads();
    float acc[8];
    const float bias = is_x ? b1[k] : 0.0f;
#pragma unroll
    for (int r = 0; r < 8; ++r) acc[r] = bias;
    for (int d = 0; d < 128; ++d) {
        float wv = w[d * 128 + k];
#pragma unroll
        for (int r = 0; r < 8; ++r) acc[r] = fmaf(rows[r][d], wv, acc[r]);
    }
    float* dst = (is_x ? xa : yb) + (size_t)r0 * 128 + k;
#pragma unroll
    for (int r = 0; r < 8; ++r) dst[r * 128] = acc[r];
}

// Kernel 2: fused pairwise MLP, r5 datapath + split accumulator chains for ILP.
// Grid 512 x 256. a_chunk = bid>>3 (16 a's via LDS), wave b-group = (bid&7)*4+wave.
__global__ __launch_bounds__(256, 2) void fused_kernel(
    const float* __restrict__ xa, const float* __restrict__ yb,
    const float* __restrict__ W2, const float* __restrict__ b2,
    const float* __restrict__ W3, const float* __restrict__ b3,
    const float* __restrict__ W4, const float* __restrict__ b4,
    float* __restrict__ out)
{
    __shared__ float xa_lds[16 * 128];

    const int tid = threadIdx.x;
    const int bid = blockIdx.x;
    const int a_chunk = bid >> 3;        // 0..63, 16 a's each
    const int bq = bid & 7;
    const int wave = tid >> 6;
    const int lane = tid & 63;
    const int half = lane >> 5;
    const int m = lane & 31;
    const int bg = bq * 4 + wave;        // 0..31

    // ---- stage xa tile (16 rows x 128 f32 = 8 KB): two f32x4 per thread ----
    {
        const f32x4* xsrc = (const f32x4*)(xa + (size_t)a_chunk * 16 * 128);
        f32x4* dst = (f32x4*)xa_lds;
        dst[tid] = xsrc[tid];
        dst[tid + 256] = xsrc[tid + 256];
    }

    // ---- y row in B-fragment order (r1 slot mapping): yv[s][0..1] = yb[row][s*16+h*8 ..]
    f32x4 yv0[8], yv1[8];
    {
        const float* yrow = yb + (size_t)(bg * 32 + m) * 128 + half * 8;
#pragma unroll
        for (int s = 0; s < 8; ++s) {
            yv0[s] = *(const f32x4*)&yrow[s * 16];
            yv1[s] = *(const f32x4*)&yrow[s * 16 + 4];
        }
    }

    // ---- loop-invariant fragments ----
    // Layer2 A = W2^T: A[m'][k], m' = lane&31 (+32*mt), k = s*16 + half*8 + j
    s16x8 W2a[2][8];
#pragma unroll
    for (int mt = 0; mt < 2; ++mt)
#pragma unroll
        for (int s = 0; s < 8; ++s)
#pragma unroll
            for (int j = 0; j < 8; ++j)
                W2a[mt][s][j] = f2bf(W2[(s * 16 + half * 8 + j) * 64 + mt * 32 + m]);

    // Layer3 A = W3^T padded M 8->32
    s16x8 W3a[4];
#pragma unroll
    for (int s = 0; s < 4; ++s)
#pragma unroll
        for (int j = 0; j < 8; ++j)
            W3a[s][j] = (m < 8) ? f2bf(W3[(s * 16 + half * 8 + j) * 8 + m]) : (short)0;

    // b2 bias as C-operand of the first chain-a MFMAs; zero C for chain-b.
    f32x16 b2v0, b2v1;
#pragma unroll
    for (int r = 0; r < 16; ++r) {
        int f = (r & 3) + 8 * (r >> 2) + 4 * half;
        b2v0[r] = b2[f];
        b2v1[r] = b2[f + 32];
    }
    const f32x16 fz = {};   // hoisted zero C (loop-invariant AGPR set)
    float b3v[4], w4v[4];
#pragma unroll
    for (int j = 0; j < 4; ++j) {
        b3v[j] = b3[j + 4 * half];
        w4v[j] = W4[j + 4 * half];
    }
    const float b4s = b4[0];

    __syncthreads();

    float* outp = out + (size_t)(a_chunk * 16) * 1024 + bg * 32 + m;

    for (int ai = 0; ai < 16; ++ai) {
        const float* xr = &xa_lds[ai * 128 + half * 8];
        f32x16 c20a, c20b, c21a, c21b;   // 4 independent L2 chains (s-parity)
#pragma unroll
        for (int s = 0; s < 8; ++s) {
            // layer-1 B-fragment, built in f32 VALU (wave-uniform x broadcast reads)
            f32x4 x0 = *(const f32x4*)&xr[s * 16];
            f32x4 x1 = *(const f32x4*)&xr[s * 16 + 4];
            f32x4 h0 = x0 + yv0[s];
            f32x4 h1 = x1 + yv1[s];
            u32x4 q;
            q.x = cvtpk(fmaxf(h0.x, 0.f), fmaxf(h0.y, 0.f));
            q.y = cvtpk(fmaxf(h0.z, 0.f), fmaxf(h0.w, 0.f));
            q.z = cvtpk(fmaxf(h1.x, 0.f), fmaxf(h1.y, 0.f));
            q.w = cvtpk(fmaxf(h1.z, 0.f), fmaxf(h1.w, 0.f));
            s16x8 bfrag = __builtin_bit_cast(s16x8, q);
            if (s == 0) {
                c20a = __builtin_amdgcn_mfma_f32_32x32x16_bf16(W2a[0][0], bfrag, b2v0, 0, 0, 0);
                c21a = __builtin_amdgcn_mfma_f32_32x32x16_bf16(W2a[1][0], bfrag, b2v1, 0, 0, 0);
            } else if (s == 1) {
                c20b = __builtin_amdgcn_mfma_f32_32x32x16_bf16(W2a[0][1], bfrag, fz, 0, 0, 0);
                c21b = __builtin_amdgcn_mfma_f32_32x32x16_bf16(W2a[1][1], bfrag, fz, 0, 0, 0);
            } else if (s & 1) {
                c20b = __builtin_amdgcn_mfma_f32_32x32x16_bf16(W2a[0][s], bfrag, c20b, 0, 0, 0);
                c21b = __builtin_amdgcn_mfma_f32_32x32x16_bf16(W2a[1][s], bfrag, c21b, 0, 0, 0);
            } else {
                c20a = __builtin_amdgcn_mfma_f32_32x32x16_bf16(W2a[0][s], bfrag, c20a, 0, 0, 0);
                c21a = __builtin_amdgcn_mfma_f32_32x32x16_bf16(W2a[1][s], bfrag, c21a, 0, 0, 0);
            }
        }

        // merge chains + relu(h2) pack; P covers features mt0, Q mt1
        unsigned P[8], Q[8];
#pragma unroll
        for (int i = 0; i < 8; ++i) {
            P[i] = cvtpk(fmaxf(c20a[2 * i] + c20b[2 * i], 0.f),
                         fmaxf(c20a[2 * i + 1] + c20b[2 * i + 1], 0.f));
            Q[i] = cvtpk(fmaxf(c21a[2 * i] + c21b[2 * i], 0.f),
                         fmaxf(c21a[2 * i + 1] + c21b[2 * i + 1], 0.f));
        }
        // C-layout -> layer-3 B-fragments (validated r1/r3/r5)
        s16x8 bf3[4];
        {
            unsigned w0 = P[0], w2 = P[2]; swap32(w0, w2);
            unsigned w1 = P[1], w3 = P[3]; swap32(w1, w3);
            u32x4 t; t.x = w0; t.y = w1; t.z = w2; t.w = w3;
            bf3[0] = __builtin_bit_cast(s16x8, t);
            unsigned v0 = P[4], v2 = P[6]; swap32(v0, v2);
            unsigned v1 = P[5], v3 = P[7]; swap32(v1, v3);
            u32x4 u; u.x = v0; u.y = v1; u.z = v2; u.w = v3;
            bf3[1] = __builtin_bit_cast(s16x8, u);
            unsigned a0 = Q[0], a2 = Q[2]; swap32(a0, a2);
            unsigned a1 = Q[1], a3 = Q[3]; swap32(a1, a3);
            u32x4 t2; t2.x = a0; t2.y = a1; t2.z = a2; t2.w = a3;
            bf3[2] = __builtin_bit_cast(s16x8, t2);
            unsigned e0 = Q[4], e2 = Q[6]; swap32(e0, e2);
            unsigned e1 = Q[5], e3 = Q[7]; swap32(e1, e3);
            u32x4 u2; u2.x = e0; u2.y = e1; u2.z = e2; u2.w = e3;
            bf3[3] = __builtin_bit_cast(s16x8, u2);
        }

        // Layer3: two independent chains of 2
        f32x16 c3a = __builtin_amdgcn_mfma_f32_32x32x16_bf16(W3a[0], bf3[0], fz, 0, 0, 0);
        f32x16 c3b = __builtin_amdgcn_mfma_f32_32x32x16_bf16(W3a[1], bf3[1], fz, 0, 0, 0);
        c3a = __builtin_amdgcn_mfma_f32_32x32x16_bf16(W3a[2], bf3[2], c3a, 0, 0, 0);
        c3b = __builtin_amdgcn_mfma_f32_32x32x16_bf16(W3a[3], bf3[3], c3b, 0, 0, 0);

        // layer4: each lane has 4 of its pair's 8 h3 features (other 4 in lane^32)
        float p = 0.f;
#pragma unroll
        for (int j = 0; j < 4; ++j)
            p = fmaf(fmaxf(c3a[j] + c3b[j] + b3v[j], 0.f), w4v[j], p);
        unsigned pu = __builtin_bit_cast(unsigned, p);
        unsigned pv = pu;
        asm("" : "+v"(pv));
        swap32(pu, pv);
        float r = __builtin_bit_cast(float, pu) + __builtin_bit_cast(float, pv) + b4s;
        if (half == 0)
            outp[(size_t)ai * 1024] = r;
    }
}

extern "C" void kernel_launch(void* const* d_in, const int* in_sizes, int n_in,
                              void* d_out, int out_size, void* d_ws, size_t ws_size,
                              hipStream_t stream) {
    const float* x  = (const float*)d_in[0];
    const float* y  = (const float*)d_in[1];
    const float* W1 = (const float*)d_in[2];
    const float* b1 = (const float*)d_in[3];
    const float* W2 = (const float*)d_in[4];
    const float* b2 = (const float*)d_in[5];
    const float* W3 = (const float*)d_in[6];
    const float* b3 = (const float*)d_in[7];
    const float* W4 = (const float*)d_in[8];
    const float* b4 = (const float*)d_in[9];
    float* out = (float*)d_out;

    float* xa = (float*)d_ws;              // 1024*128 f32
    float* yb = xa + 1024 * 128;           // 1024*128 f32

    precompute_kernel<<<dim3(256), dim3(128), 0, stream>>>(x, y, W1, b1, xa, yb);
    fused_kernel<<<dim3(512), dim3(256), 0, stream>>>(xa, yb, W2, b2, W3, b3, W4, b4, out);
}

// Round 7
// 42.971 us; speedup vs baseline: 1.1053x; 1.1053x over previous
//
#include <hip/hip_runtime.h>
#include <hip/hip_bf16.h>

typedef float f32x4 __attribute__((ext_vector_type(4)));
typedef float f32x16 __attribute__((ext_vector_type(16)));
typedef short s16x8 __attribute__((ext_vector_type(8)));
typedef unsigned int u32x4 __attribute__((ext_vector_type(4)));

__device__ __forceinline__ short f2bf(float v) {
    __hip_bfloat16 h = __float2bfloat16(v);
    return __builtin_bit_cast(short, h);
}
__device__ __forceinline__ unsigned cvtpk(float lo, float hi) {
    unsigned r;
    asm("v_cvt_pk_bf16_f32 %0, %1, %2" : "=v"(r) : "v"(lo), "v"(hi));
    return r;
}
// v_permlane32_swap_b32: x <- {x_lo, y_lo}, y <- {x_hi, y_hi}
__device__ __forceinline__ void swap32(unsigned &x, unsigned &y) {
    asm("v_permlane32_swap_b32 %0, %1" : "+v"(x), "+v"(y));
}

// Kernel 1: xa[a][k] = b1[k] + sum_d x[a][d]*W1[d][k];  yb[b][k] = sum_d y[b][d]*W1[128+d][k]
__global__ __launch_bounds__(128) void precompute_kernel(
    const float* __restrict__ x, const float* __restrict__ y,
    const float* __restrict__ W1, const float* __restrict__ b1,
    float* __restrict__ xa, float* __restrict__ yb)
{
    __shared__ float rows[8][128];
    const int bid = blockIdx.x;
    const int k = threadIdx.x;
    const bool is_x = bid < 128;
    const int r0 = (is_x ? bid : bid - 128) * 8;
    const float* src = (is_x ? x : y) + (size_t)r0 * 128;
    const float* w = is_x ? W1 : (W1 + 128 * 128);
#pragma unroll
    for (int r = 0; r < 8; ++r) rows[r][k] = src[r * 128 + k];
    __syncthreads();
    float acc[8];
    const float bias = is_x ? b1[k] : 0.0f;
#pragma unroll
    for (int r = 0; r < 8; ++r) acc[r] = bias;
    for (int d = 0; d < 128; ++d) {
        float wv = w[d * 128 + k];
#pragma unroll
        for (int r = 0; r < 8; ++r) acc[r] = fmaf(rows[r][d], wv, acc[r]);
    }
    float* dst = (is_x ? xa : yb) + (size_t)r0 * 128 + k;
#pragma unroll
    for (int r = 0; r < 8; ++r) dst[r * 128] = acc[r];
}

// Kernel 2: fused pairwise MLP. r5-validated datapath; ai loop unrolled x2 so the
// scheduler can overlap iteration i's MFMA latency with iteration i+1's VALU work
// (iterations are independent: different a-row, same y registers/weights).
// Grid 512 x 256. a_chunk = bid>>3 (16 a's via LDS), wave b-group = (bid&7)*4+wave.
__global__ __launch_bounds__(256, 2) void fused_kernel(
    const float* __restrict__ xa, const float* __restrict__ yb,
    const float* __restrict__ W2, const float* __restrict__ b2,
    const float* __restrict__ W3, const float* __restrict__ b3,
    const float* __restrict__ W4, const float* __restrict__ b4,
    float* __restrict__ out)
{
    __shared__ float xa_lds[16 * 128];

    const int tid = threadIdx.x;
    const int bid = blockIdx.x;
    const int a_chunk = bid >> 3;        // 0..63, 16 a's each
    const int bq = bid & 7;
    const int wave = tid >> 6;
    const int lane = tid & 63;
    const int half = lane >> 5;
    const int m = lane & 31;
    const int bg = bq * 4 + wave;        // 0..31

    // ---- stage xa tile (16 rows x 128 f32 = 8 KB): two f32x4 per thread ----
    {
        const f32x4* xsrc = (const f32x4*)(xa + (size_t)a_chunk * 16 * 128);
        f32x4* dst = (f32x4*)xa_lds;
        dst[tid] = xsrc[tid];
        dst[tid + 256] = xsrc[tid + 256];
    }

    // ---- y row in B-fragment order (r1 slot mapping): yv[s][0..1] = yb[row][s*16+h*8 ..]
    f32x4 yv0[8], yv1[8];
    {
        const float* yrow = yb + (size_t)(bg * 32 + m) * 128 + half * 8;
#pragma unroll
        for (int s = 0; s < 8; ++s) {
            yv0[s] = *(const f32x4*)&yrow[s * 16];
            yv1[s] = *(const f32x4*)&yrow[s * 16 + 4];
        }
    }

    // ---- loop-invariant fragments ----
    // Layer2 A = W2^T: A[m'][k], m' = lane&31 (+32*mt), k = s*16 + half*8 + j
    s16x8 W2a[2][8];
#pragma unroll
    for (int mt = 0; mt < 2; ++mt)
#pragma unroll
        for (int s = 0; s < 8; ++s)
#pragma unroll
            for (int j = 0; j < 8; ++j)
                W2a[mt][s][j] = f2bf(W2[(s * 16 + half * 8 + j) * 64 + mt * 32 + m]);

    // Layer3 A = W3^T padded M 8->32
    s16x8 W3a[4];
#pragma unroll
    for (int s = 0; s < 4; ++s)
#pragma unroll
        for (int j = 0; j < 8; ++j)
            W3a[s][j] = (m < 8) ? f2bf(W3[(s * 16 + half * 8 + j) * 8 + m]) : (short)0;

    // biases as C-operands (fed to the FIRST MFMA of each chain - zero movs/ai)
    f32x16 b2v0, b2v1, c3init;
#pragma unroll
    for (int r = 0; r < 16; ++r) {
        int f = (r & 3) + 8 * (r >> 2) + 4 * half;
        b2v0[r] = b2[f];
        b2v1[r] = b2[f + 32];
        c3init[r] = (r < 4) ? b3[(r & 3) + 4 * half] : 0.0f;
    }
    float w4v[4];
#pragma unroll
    for (int j = 0; j < 4; ++j) w4v[j] = W4[j + 4 * half];
    const float b4s = b4[0];

    __syncthreads();

    float* outp = out + (size_t)(a_chunk * 16) * 1024 + bg * 32 + m;

#pragma unroll 2
    for (int ai = 0; ai < 16; ++ai) {
        const float* xr = &xa_lds[ai * 128 + half * 8];
        f32x16 c20, c21;
#pragma unroll
        for (int s = 0; s < 8; ++s) {
            // layer-1 B-fragment, built in f32 VALU (wave-uniform x broadcast reads)
            f32x4 x0 = *(const f32x4*)&xr[s * 16];
            f32x4 x1 = *(const f32x4*)&xr[s * 16 + 4];
            f32x4 h0 = x0 + yv0[s];
            f32x4 h1 = x1 + yv1[s];
            u32x4 q;
            q.x = cvtpk(fmaxf(h0.x, 0.f), fmaxf(h0.y, 0.f));
            q.y = cvtpk(fmaxf(h0.z, 0.f), fmaxf(h0.w, 0.f));
            q.z = cvtpk(fmaxf(h1.x, 0.f), fmaxf(h1.y, 0.f));
            q.w = cvtpk(fmaxf(h1.z, 0.f), fmaxf(h1.w, 0.f));
            s16x8 bfrag = __builtin_bit_cast(s16x8, q);
            if (s == 0) {   // bias enters as the C operand of the first MFMA
                c20 = __builtin_amdgcn_mfma_f32_32x32x16_bf16(W2a[0][0], bfrag, b2v0, 0, 0, 0);
                c21 = __builtin_amdgcn_mfma_f32_32x32x16_bf16(W2a[1][0], bfrag, b2v1, 0, 0, 0);
            } else {
                c20 = __builtin_amdgcn_mfma_f32_32x32x16_bf16(W2a[0][s], bfrag, c20, 0, 0, 0);
                c21 = __builtin_amdgcn_mfma_f32_32x32x16_bf16(W2a[1][s], bfrag, c21, 0, 0, 0);
            }
        }

        // relu(h2) pack; P covers features mt0, Q mt1
        unsigned P[8], Q[8];
#pragma unroll
        for (int i = 0; i < 8; ++i) {
            P[i] = cvtpk(fmaxf(c20[2 * i], 0.f), fmaxf(c20[2 * i + 1], 0.f));
            Q[i] = cvtpk(fmaxf(c21[2 * i], 0.f), fmaxf(c21[2 * i + 1], 0.f));
        }
        // C-layout -> layer-3 B-fragments (validated r1/r3/r5)
        s16x8 bf3[4];
        {
            unsigned w0 = P[0], w2 = P[2]; swap32(w0, w2);
            unsigned w1 = P[1], w3 = P[3]; swap32(w1, w3);
            u32x4 t; t.x = w0; t.y = w1; t.z = w2; t.w = w3;
            bf3[0] = __builtin_bit_cast(s16x8, t);
            unsigned v0 = P[4], v2 = P[6]; swap32(v0, v2);
            unsigned v1 = P[5], v3 = P[7]; swap32(v1, v3);
            u32x4 u; u.x = v0; u.y = v1; u.z = v2; u.w = v3;
            bf3[1] = __builtin_bit_cast(s16x8, u);
            unsigned a0 = Q[0], a2 = Q[2]; swap32(a0, a2);
            unsigned a1 = Q[1], a3 = Q[3]; swap32(a1, a3);
            u32x4 t2; t2.x = a0; t2.y = a1; t2.z = a2; t2.w = a3;
            bf3[2] = __builtin_bit_cast(s16x8, t2);
            unsigned e0 = Q[4], e2 = Q[6]; swap32(e0, e2);
            unsigned e1 = Q[5], e3 = Q[7]; swap32(e1, e3);
            u32x4 u2; u2.x = e0; u2.y = e1; u2.z = e2; u2.w = e3;
            bf3[3] = __builtin_bit_cast(s16x8, u2);
        }

        f32x16 c3 = __builtin_amdgcn_mfma_f32_32x32x16_bf16(W3a[0], bf3[0], c3init, 0, 0, 0);
#pragma unroll
        for (int s = 1; s < 4; ++s)
            c3 = __builtin_amdgcn_mfma_f32_32x32x16_bf16(W3a[s], bf3[s], c3, 0, 0, 0);

        // layer4: each lane has 4 of its pair's 8 h3 features (other 4 in lane^32)
        float p = fmaxf(c3[0], 0.f) * w4v[0] + fmaxf(c3[1], 0.f) * w4v[1]
                + fmaxf(c3[2], 0.f) * w4v[2] + fmaxf(c3[3], 0.f) * w4v[3];
        unsigned pu = __builtin_bit_cast(unsigned, p);
        unsigned pv = pu;
        asm("" : "+v"(pv));
        swap32(pu, pv);
        float r = __builtin_bit_cast(float, pu) + __builtin_bit_cast(float, pv) + b4s;
        if (half == 0)
            outp[(size_t)ai * 1024] = r;
    }
}

extern "C" void kernel_launch(void* const* d_in, const int* in_sizes, int n_in,
                              void* d_out, int out_size, void* d_ws, size_t ws_size,
                              hipStream_t stream) {
    const float* x  = (const float*)d_in[0];
    const float* y  = (const float*)d_in[1];
    const float* W1 = (const float*)d_in[2];
    const float* b1 = (const float*)d_in[3];
    const float* W2 = (const float*)d_in[4];
    const float* b2 = (const float*)d_in[5];
    const float* W3 = (const float*)d_in[6];
    const float* b3 = (const float*)d_in[7];
    const float* W4 = (const float*)d_in[8];
    const float* b4 = (const float*)d_in[9];
    float* out = (float*)d_out;

    float* xa = (float*)d_ws;              // 1024*128 f32
    float* yb = xa + 1024 * 128;           // 1024*128 f32

    precompute_kernel<<<dim3(256), dim3(128), 0, stream>>>(x, y, W1, b1, xa, yb);
    fused_kernel<<<dim3(512), dim3(256), 0, stream>>>(xa, yb, W2, b2, W3, b3, W4, b4, out);
}

// Round 8
// 41.610 us; speedup vs baseline: 1.1415x; 1.0327x over previous
//
#include <hip/hip_runtime.h>
#include <hip/hip_bf16.h>

typedef float f32x4 __attribute__((ext_vector_type(4)));
typedef float f32x16 __attribute__((ext_vector_type(16)));
typedef short s16x8 __attribute__((ext_vector_type(8)));
typedef unsigned int u32x4 __attribute__((ext_vector_type(4)));

__device__ __forceinline__ unsigned cvtpk(float lo, float hi) {
    unsigned r;
    asm("v_cvt_pk_bf16_f32 %0, %1, %2" : "=v"(r) : "v"(lo), "v"(hi));
    return r;
}
// v_permlane32_swap_b32: x <- {x_lo, y_lo}, y <- {x_hi, y_hi}
__device__ __forceinline__ void swap32(unsigned &x, unsigned &y) {
    asm("v_permlane32_swap_b32 %0, %1" : "+v"(x), "+v"(y));
}

// Kernel 1: xa[a][k] = b1[k] + sum_d x[a][d]*W1[d][k];  yb[b][k] = sum_d y[b][d]*W1[128+d][k]
__global__ __launch_bounds__(128) void precompute_kernel(
    const float* __restrict__ x, const float* __restrict__ y,
    const float* __restrict__ W1, const float* __restrict__ b1,
    float* __restrict__ xa, float* __restrict__ yb)
{
    __shared__ float rows[8][128];
    const int bid = blockIdx.x;
    const int k = threadIdx.x;
    const bool is_x = bid < 128;
    const int r0 = (is_x ? bid : bid - 128) * 8;
    const float* src = (is_x ? x : y) + (size_t)r0 * 128;
    const float* w = is_x ? W1 : (W1 + 128 * 128);
#pragma unroll
    for (int r = 0; r < 8; ++r) rows[r][k] = src[r * 128 + k];
    __syncthreads();
    float acc[8];
    const float bias = is_x ? b1[k] : 0.0f;
#pragma unroll
    for (int r = 0; r < 8; ++r) acc[r] = bias;
    for (int d = 0; d < 128; ++d) {
        float wv = w[d * 128 + k];
#pragma unroll
        for (int r = 0; r < 8; ++r) acc[r] = fmaf(rows[r][d], wv, acc[r]);
    }
    float* dst = (is_x ? xa : yb) + (size_t)r0 * 128 + k;
#pragma unroll
    for (int r = 0; r < 8; ++r) dst[r * 128] = acc[r];
}

// Kernel 2: fused pairwise MLP, r5 datapath with weights/biases in LDS tables
// (frees ~112 resident regs -> 3 waves/SIMD). Grid 1024 x 256.
// a_chunk = bid>>3 (8 a's via LDS), wave b-group = (bid&7)*4+wave (y in regs).
__global__ __launch_bounds__(256, 3) void fused_kernel(
    const float* __restrict__ xa, const float* __restrict__ yb,
    const float* __restrict__ W2, const float* __restrict__ b2,
    const float* __restrict__ W3, const float* __restrict__ b3,
    const float* __restrict__ W4, const float* __restrict__ b4,
    float* __restrict__ out)
{
    __shared__ float xa_lds[8 * 128];                         // 4 KB
    __shared__ __align__(16) short w2_lds[2 * 8 * 64 * 8];    // 16 KB: [mt][s][lane][8]
    __shared__ __align__(16) short w3_lds[4 * 64 * 8];        // 4 KB:  [s][lane][8]
    __shared__ __align__(64) float b2_lds[64];                // [mt][half][16] C-layout
    __shared__ __align__(64) float b3_lds[32];                // [half][16] C-layout (r>=4 zero)

    const int tid = threadIdx.x;
    const int bid = blockIdx.x;
    const int a_chunk = bid >> 3;        // 0..127, 8 a's each
    const int bq = bid & 7;
    const int wave = tid >> 6;
    const int lane = tid & 63;
    const int half = lane >> 5;
    const int m = lane & 31;
    const int bg = bq * 4 + wave;        // 0..31

    // ---- stage xa tile (8 rows x 128 f32 = 4 KB) ----
    {
        const f32x4* xsrc = (const f32x4*)(xa + (size_t)a_chunk * 8 * 128);
        ((f32x4*)xa_lds)[tid] = xsrc[tid];
    }
    // ---- W2 fragment table: entry (mt,s,l)[j] = bf16(W2[(s*16+(l>>5)*8+j)*64 + mt*32 + (l&31)])
#pragma unroll
    for (int k = 0; k < 4; ++k) {
        int e = tid + 256 * k;
        int l = e & 63, s = (e >> 6) & 7, mt = e >> 9;
        int col = mt * 32 + (l & 31);
        int krow = s * 16 + (l >> 5) * 8;
        u32x4 q;
#pragma unroll
        for (int jj = 0; jj < 4; ++jj)
            q[jj] = cvtpk(W2[(krow + 2 * jj) * 64 + col], W2[(krow + 2 * jj + 1) * 64 + col]);
        *(u32x4*)&w2_lds[e * 8] = q;
    }
    // ---- W3 fragment table (M padded 8->32): one entry per thread ----
    {
        int l = tid & 63, s = tid >> 6;
        int row = l & 31;
        int krow = s * 16 + (l >> 5) * 8;
        u32x4 q;
#pragma unroll
        for (int jj = 0; jj < 4; ++jj) {
            float lo = (row < 8) ? W3[(krow + 2 * jj) * 8 + row] : 0.f;
            float hi = (row < 8) ? W3[(krow + 2 * jj + 1) * 8 + row] : 0.f;
            q[jj] = cvtpk(lo, hi);
        }
        *(u32x4*)&w3_lds[tid * 8] = q;
    }
    if (tid < 64)
        b2_lds[tid] = b2[(tid & 3) + 8 * ((tid >> 2) & 3) + 4 * ((tid >> 4) & 1) + 32 * (tid >> 5)];
    if (tid < 32)
        b3_lds[tid] = ((tid & 15) < 4) ? b3[(tid & 3) + 4 * (tid >> 4)] : 0.f;

    // ---- y row in B-fragment order (r1/r5 slot mapping), registers ----
    f32x4 yv0[8], yv1[8];
    {
        const float* yrow = yb + (size_t)(bg * 32 + m) * 128 + half * 8;
#pragma unroll
        for (int s = 0; s < 8; ++s) {
            yv0[s] = *(const f32x4*)&yrow[s * 16];
            yv1[s] = *(const f32x4*)&yrow[s * 16 + 4];
        }
    }
    float w4v[4];
#pragma unroll
    for (int j = 0; j < 4; ++j) w4v[j] = W4[j + 4 * half];
    const float b4s = b4[0];

    __syncthreads();

    const short* w2p = &w2_lds[lane * 8];
    const short* w3p = &w3_lds[lane * 8];
    float* outp = out + (size_t)(a_chunk * 8) * 1024 + bg * 32 + m;

    for (int ai = 0; ai < 8; ++ai) {
        const float* xr = &xa_lds[ai * 128 + half * 8];
        f32x16 c20, c21;
#pragma unroll
        for (int s = 0; s < 8; ++s) {
            // layer-1 B-fragment, f32 VALU (r5-validated datapath)
            f32x4 x0 = *(const f32x4*)&xr[s * 16];
            f32x4 x1 = *(const f32x4*)&xr[s * 16 + 4];
            f32x4 h0 = x0 + yv0[s];
            f32x4 h1 = x1 + yv1[s];
            u32x4 q;
            q.x = cvtpk(fmaxf(h0.x, 0.f), fmaxf(h0.y, 0.f));
            q.y = cvtpk(fmaxf(h0.z, 0.f), fmaxf(h0.w, 0.f));
            q.z = cvtpk(fmaxf(h1.x, 0.f), fmaxf(h1.y, 0.f));
            q.w = cvtpk(fmaxf(h1.z, 0.f), fmaxf(h1.w, 0.f));
            s16x8 bfrag = __builtin_bit_cast(s16x8, q);
            s16x8 wf0 = *(const s16x8*)(w2p + s * 512);          // mt0 frag
            s16x8 wf1 = *(const s16x8*)(w2p + (8 + s) * 512);    // mt1 frag
            if (s == 0) {   // b2 bias enters as the C operand (LDS broadcast reads)
                c20 = __builtin_amdgcn_mfma_f32_32x32x16_bf16(
                    wf0, bfrag, *(const f32x16*)&b2_lds[half * 16], 0, 0, 0);
                c21 = __builtin_amdgcn_mfma_f32_32x32x16_bf16(
                    wf1, bfrag, *(const f32x16*)&b2_lds[32 + half * 16], 0, 0, 0);
            } else {
                c20 = __builtin_amdgcn_mfma_f32_32x32x16_bf16(wf0, bfrag, c20, 0, 0, 0);
                c21 = __builtin_amdgcn_mfma_f32_32x32x16_bf16(wf1, bfrag, c21, 0, 0, 0);
            }
        }

        // relu(h2) pack; P covers features mt0, Q mt1
        unsigned P[8], Q[8];
#pragma unroll
        for (int i = 0; i < 8; ++i) {
            P[i] = cvtpk(fmaxf(c20[2 * i], 0.f), fmaxf(c20[2 * i + 1], 0.f));
            Q[i] = cvtpk(fmaxf(c21[2 * i], 0.f), fmaxf(c21[2 * i + 1], 0.f));
        }
        // C-layout -> layer-3 B-fragments (validated r1/r3/r5)
        s16x8 bf3[4];
        {
            unsigned w0 = P[0], w2 = P[2]; swap32(w0, w2);
            unsigned w1 = P[1], w3 = P[3]; swap32(w1, w3);
            u32x4 t; t.x = w0; t.y = w1; t.z = w2; t.w = w3;
            bf3[0] = __builtin_bit_cast(s16x8, t);
            unsigned v0 = P[4], v2 = P[6]; swap32(v0, v2);
            unsigned v1 = P[5], v3 = P[7]; swap32(v1, v3);
            u32x4 u; u.x = v0; u.y = v1; u.z = v2; u.w = v3;
            bf3[1] = __builtin_bit_cast(s16x8, u);
            unsigned a0 = Q[0], a2 = Q[2]; swap32(a0, a2);
            unsigned a1 = Q[1], a3 = Q[3]; swap32(a1, a3);
            u32x4 t2; t2.x = a0; t2.y = a1; t2.z = a2; t2.w = a3;
            bf3[2] = __builtin_bit_cast(s16x8, t2);
            unsigned e0 = Q[4], e2 = Q[6]; swap32(e0, e2);
            unsigned e1 = Q[5], e3 = Q[7]; swap32(e1, e3);
            u32x4 u2; u2.x = e0; u2.y = e1; u2.z = e2; u2.w = e3;
            bf3[3] = __builtin_bit_cast(s16x8, u2);
        }

        // Layer3: b3 bias as C of the first MFMA (LDS broadcast read)
        f32x16 c3 = __builtin_amdgcn_mfma_f32_32x32x16_bf16(
            *(const s16x8*)(w3p + 0 * 512), bf3[0],
            *(const f32x16*)&b3_lds[half * 16], 0, 0, 0);
#pragma unroll
        for (int s = 1; s < 4; ++s)
            c3 = __builtin_amdgcn_mfma_f32_32x32x16_bf16(
                *(const s16x8*)(w3p + s * 512), bf3[s], c3, 0, 0, 0);

        // layer4: each lane has 4 of its pair's 8 h3 features (other 4 in lane^32)
        float p = fmaxf(c3[0], 0.f) * w4v[0] + fmaxf(c3[1], 0.f) * w4v[1]
                + fmaxf(c3[2], 0.f) * w4v[2] + fmaxf(c3[3], 0.f) * w4v[3];
        unsigned pu = __builtin_bit_cast(unsigned, p);
        unsigned pv = pu;
        asm("" : "+v"(pv));
        swap32(pu, pv);
        float r = __builtin_bit_cast(float, pu) + __builtin_bit_cast(float, pv) + b4s;
        if (half == 0)
            outp[(size_t)ai * 1024] = r;
    }
}

extern "C" void kernel_launch(void* const* d_in, const int* in_sizes, int n_in,
                              void* d_out, int out_size, void* d_ws, size_t ws_size,
                              hipStream_t stream) {
    const float* x  = (const float*)d_in[0];
    const float* y  = (const float*)d_in[1];
    const float* W1 = (const float*)d_in[2];
    const float* b1 = (const float*)d_in[3];
    const float* W2 = (const float*)d_in[4];
    const float* b2 = (const float*)d_in[5];
    const float* W3 = (const float*)d_in[6];
    const float* b3 = (const float*)d_in[7];
    const float* W4 = (const float*)d_in[8];
    const float* b4 = (const float*)d_in[9];
    float* out = (float*)d_out;

    float* xa = (float*)d_ws;              // 1024*128 f32
    float* yb = xa + 1024 * 128;           // 1024*128 f32

    precompute_kernel<<<dim3(256), dim3(128), 0, stream>>>(x, y, W1, b1, xa, yb);
    fused_kernel<<<dim3(1024), dim3(256), 0, stream>>>(xa, yb, W2, b2, W3, b3, W4, b4, out);
}